// Round 14
// baseline (123.652 us; speedup 1.0000x reference)
//
#include <hip/hip_runtime.h>
#include <cstdint>

#define B_SZ 8192
#define D_SZ 512
#define K_SZ 2048
#define EPSV 1e-8f
// 1/TEMP
#define INV_T 2.0f

typedef float floatx16 __attribute__((ext_vector_type(16)));
typedef int intx8 __attribute__((ext_vector_type(8)));

// async global->LDS, 16B per lane. LDS dest must be wave-uniform base + lane*16.
__device__ __forceinline__ void async_cp16(const void* g, void* l) {
    typedef __attribute__((address_space(1))) unsigned int gds_t;
    typedef __attribute__((address_space(3))) unsigned int lds_t;
    __builtin_amdgcn_global_load_lds((gds_t*)(unsigned long long)g, (lds_t*)l, 16, 0, 0);
}

// pack 8 fp32 -> 8 fp8 e4m3 (OCP, RNE, saturating) as int2
__device__ __forceinline__ int2 pack_fp8x8(float4 a0, float4 a1) {
    int w0 = __builtin_amdgcn_cvt_pk_fp8_f32(a0.x, a0.y, 0, false);
    w0 = __builtin_amdgcn_cvt_pk_fp8_f32(a0.z, a0.w, w0, true);
    int w1 = __builtin_amdgcn_cvt_pk_fp8_f32(a1.x, a1.y, 0, false);
    w1 = __builtin_amdgcn_cvt_pk_fp8_f32(a1.z, a1.w, w1, true);
    return make_int2(w0, w1);
}

// ---------------------------------------------------------------------------
// Kernel 1 (merged prep+gather+bounds):
//  blocks [0,2048):  anchor prep: norms, pos logit, z_i -> fp8 A; blocks
//    [0,64) zero rowacc; block 0 zeroes d_out.
//  blocks [2048,3072): gather pair k = g>>1, candidate h = g&1 of z_j ->
//    fp8 G stored SORTED BY c0 (rank = #{c0' < c0}, counted over perm) at
//    row 2*rank + h; smeta[rank] = {1/nj(c), 1/nj(c+1), c0}.
//  block 3072: panel bounds pbound[2p]=#{c0<128p}, pbound[2p+1]=#{c0<128p+127}.
// ---------------------------------------------------------------------------
__global__ __launch_bounds__(256) void k_prep(
    const float* __restrict__ zi, const float* __restrict__ zj,
    const int* __restrict__ perm,
    float* __restrict__ ri_arr, float* __restrict__ pos_arr,
    unsigned char* __restrict__ A,
    float4* __restrict__ smeta, unsigned char* __restrict__ G,
    int* __restrict__ pbound,
    float* __restrict__ rowacc, float* __restrict__ out)
{
    int w = threadIdx.x >> 6, l = threadIdx.x & 63;
    if (blockIdx.x < 2048) {
        if (blockIdx.x < 64)
            rowacc[blockIdx.x * 256 + threadIdx.x] = 0.f;   // pe[8192] ++ pc[8192]
        if (blockIdx.x == 0 && threadIdx.x < 3) out[threadIdx.x] = 0.f;
        int row = blockIdx.x * 4 + w;
        const float4* zi4 = (const float4*)(zi + (size_t)row * D_SZ);
        const float4* zj4 = (const float4*)(zj + (size_t)row * D_SZ);
        float4 a0 = zi4[2 * l], a1 = zi4[2 * l + 1];
        float4 b0 = zj4[2 * l], b1 = zj4[2 * l + 1];
        float si = a0.x * a0.x + a0.y * a0.y + a0.z * a0.z + a0.w * a0.w
                 + a1.x * a1.x + a1.y * a1.y + a1.z * a1.z + a1.w * a1.w;
        float sj = b0.x * b0.x + b0.y * b0.y + b0.z * b0.z + b0.w * b0.w
                 + b1.x * b1.x + b1.y * b1.y + b1.z * b1.z + b1.w * b1.w;
        float dd = a0.x * b0.x + a0.y * b0.y + a0.z * b0.z + a0.w * b0.w
                 + a1.x * b1.x + a1.y * b1.y + a1.z * b1.z + a1.w * b1.w;
        for (int m = 1; m < 64; m <<= 1) {
            si += __shfl_xor(si, m);
            sj += __shfl_xor(sj, m);
            dd += __shfl_xor(dd, m);
        }
        if (l == 0) {
            float ni = sqrtf(si), nj = sqrtf(sj);
            ri_arr[row] = INV_T / fmaxf(ni, 1e-6f);   // norms ~22; eps never binds
            pos_arr[row] = dd / fmaxf(ni * nj, EPSV) * INV_T;
        }
        *(int2*)(A + (size_t)row * D_SZ + l * 8) = pack_fp8x8(a0, a1);
    } else if (blockIdx.x < 3072) {
        __shared__ float srj[4];
        __shared__ int srank[4];
        int g = (blockIdx.x - 2048) * 4 + w;        // 0..4095
        int k = g >> 1, h = g & 1;
        int c0 = perm[k];
        int c = c0 + h;                             // actual z_j row
        // rank = #{c0' < c0} over the 2048 perm entries (all distinct)
        int cnt = 0;
        #pragma unroll 8
        for (int j = 0; j < 32; ++j)
            cnt += (perm[j * 64 + l] < c0) ? 1 : 0;
        for (int m = 1; m < 64; m <<= 1) cnt += __shfl_xor(cnt, m);
        int s = cnt;                                // sorted position 0..2047
        const float4* src = (const float4*)(zj + (size_t)c * D_SZ);
        float4 a0 = src[2 * l], a1 = src[2 * l + 1];
        float sm = a0.x * a0.x + a0.y * a0.y + a0.z * a0.z + a0.w * a0.w
                 + a1.x * a1.x + a1.y * a1.y + a1.z * a1.z + a1.w * a1.w;
        for (int m = 1; m < 64; m <<= 1) sm += __shfl_xor(sm, m);
        if (l == 0) { srj[w] = 1.0f / fmaxf(sqrtf(sm), 1e-6f); srank[w] = s; }
        __syncthreads();
        if ((w & 1) == 0 && l == 0)
            smeta[srank[w]] = make_float4(srj[w], srj[w + 1],
                                          __int_as_float(c0), 0.f);
        *(int2*)(G + (size_t)(2 * s + h) * D_SZ + l * 8) = pack_fp8x8(a0, a1);
    } else {
        // panel bounds: measure m = tid>>1 (0..127), half = tid&1
        __shared__ int part[256];
        int m = threadIdx.x >> 1, half = threadIdx.x & 1;
        int p = m >> 1, which = m & 1;
        int thr = p * 128 + (which ? 127 : 0);
        int cnt = 0;
        #pragma unroll 8
        for (int j = half * 1024; j < half * 1024 + 1024; ++j)
            cnt += (perm[j] < thr) ? 1 : 0;
        part[threadIdx.x] = cnt;
        __syncthreads();
        if (half == 0) pbound[m] = part[threadIdx.x] + part[threadIdx.x + 1];
    }
}

// ---------------------------------------------------------------------------
// Kernel 2: MX-fp8 MFMA GEMM, TRANSPOSED OUTPUT, SORTED-SELECTION (half work).
// 1024 blocks: (panel, ktile) over 64 anchor panels x 16 tiles of 128 sorted
// pairs. Per tile, selection vs the panel is BLOCK-UNIFORM except when the
// c0-boundary falls inside the tile:
//   LOW  (s0+128 <= bLow):  all anchors use candidate c0   -> stage rows 2s
//   HIGH (s0 >= bHigh):     all anchors use candidate c0+1 -> stage rows 2s+1
//   MIXED: two passes of 64 pairs each, both candidates staged, per-element
//          pair-select (the proven R13 epilogue).
// MFMA count, ds_read, and staging all ~halve vs R13.
// v_mfma_scale_f32_32x32x64_f8f6f4 unit scales; dbuf LDS 2x(8+8) KB; 16B
// chunk swizzle slot = c ^ ((r^(r>>2))&3) (0 conflicts measured); epilogue
// atomicAdds pe/pc into rowacc.
// XCD mapping: xcd = bid&7 owns ktiles {2x,2x+1} (256 KB sorted G, L2-
// resident); panels walked in lockstep across XCDs (A LLC-broadcast).
// ---------------------------------------------------------------------------
__global__ __launch_bounds__(256, 4) void k_gemm(
    const unsigned char* __restrict__ A,    // [8192][512] fp8  (anchors)
    const unsigned char* __restrict__ G,    // [4096][512] fp8  (sorted pairs)
    const float4* __restrict__ smeta,       // [2048]  {rj0, rj1, c0f, -}
    const int* __restrict__ pbound,         // [128]   panel bounds
    const float* __restrict__ ri_arr,       // [8192]  INV_T/ni
    const float* __restrict__ pos_arr,      // [8192]
    float* __restrict__ rowacc)             // [2][8192] atomic accumulators
{
    __shared__ unsigned char Asl[2][128 * 64];   // anchor tile, 8 KB per buffer
    __shared__ unsigned char Gsl[2][128 * 64];   // g tile
    const int tid = threadIdx.x;
    const int l = tid & 63, w = tid >> 6;
    const int wm = w >> 1, wn = w & 1;      // wm: g-half, wn: anchor-half
    const int ln = l & 31, q = l >> 5;      // 32x32 MFMA lane decomposition

    // block -> (panel, ktile), XCD-aware
    const int bid = blockIdx.x;
    const int xcd = bid & 7;
    const int slot = bid >> 3;              // 0..127
    const int kt = xcd * 2 + (slot & 1);    // 0..15
    const int panel = slot >> 1;            // 0..63
    const int aBase = panel * 128;
    const int s0 = kt * 128;

    const int bLow = pbound[2 * panel], bHigh = pbound[2 * panel + 1];
    int nPass = 2, hSel = 0;
    if (s0 + 128 <= bLow)      { nPass = 1; hSel = 0; }   // all use c0
    else if (s0 >= bHigh)      { nPass = 1; hSel = 1; }   // all use c0+1

    // staging constants: chunk fc = it*256+tid; tile row r = fc>>2
    int rIt[2], sccIt[2], ldsOffIt[2];
    size_t aOffIt[2];
    #pragma unroll
    for (int it = 0; it < 2; ++it) {
        int fc = it * 256 + tid;
        int r = fc >> 2, sâ = fc & 3;
        int scc = sâ ^ ((r ^ (r >> 2)) & 3);
        rIt[it] = r; sccIt[it] = scc * 16; ldsOffIt[it] = fc * 16;
        aOffIt[it] = (size_t)(aBase + r) * D_SZ + scc * 16;
    }

    // frag read addresses (bytes in an 8 KB buffer)
    int aAddr[2][2], gAddr[2][2];           // [t][chunk half]
    #pragma unroll
    for (int t = 0; t < 2; ++t) {
        int ar = wn * 64 + t * 32 + ln;     // anchor row (N-operand)
        int xa = (ar ^ (ar >> 2)) & 3;
        aAddr[t][0] = ar * 64 + ((2 * q) ^ xa) * 16;
        aAddr[t][1] = ar * 64 + ((2 * q + 1) ^ xa) * 16;
        int gr = wm * 64 + t * 32 + ln;     // g row (M-operand)
        int xg = (gr ^ (gr >> 2)) & 3;
        gAddr[t][0] = gr * 64 + ((2 * q) ^ xg) * 16;
        gAddr[t][1] = gr * 64 + ((2 * q + 1) ^ xg) * 16;
    }

    // per-pass G source row for tile row r
    auto gSrcRow = [&](int u, int r) -> int {
        return (nPass == 1) ? (2 * (s0 + r) + hSel) : (2 * s0 + u * 128 + r);
    };

    // anchors + per-anchor state
    int anc[2]; float riv[2], pv[2], pe[2] = {0.f, 0.f}, pc[2] = {0.f, 0.f};
    #pragma unroll
    for (int tn = 0; tn < 2; ++tn) {
        anc[tn] = aBase + wn * 64 + tn * 32 + ln;
        riv[tn] = ri_arr[anc[tn]];          // INV_T / ni
        pv[tn] = pos_arr[anc[tn]];
    }

    floatx16 acc[2][2] = {};

    // prologue: stage iter 0 into buffer 0
    #pragma unroll
    for (int it = 0; it < 2; ++it) {
        async_cp16(A + aOffIt[it], &Asl[0][ldsOffIt[it]]);
        async_cp16(G + (size_t)gSrcRow(0, rIt[it]) * D_SZ + sccIt[it],
                   &Gsl[0][ldsOffIt[it]]);
    }

    const int iterTotal = nPass * 8;
    #pragma unroll 1
    for (int iter = 0; iter < iterTotal; ++iter) {
        const int cur = iter & 1, nxt = cur ^ 1;
        const int dblk = iter & 7;
        __syncthreads();                    // staged data for `cur` is ready
        if (iter + 1 < iterTotal) {
            int nu = (iter + 1) >> 3, nd = (iter + 1) & 7;
            #pragma unroll
            for (int it = 0; it < 2; ++it) {
                async_cp16(A + aOffIt[it] + (size_t)nd * 64,
                           &Asl[nxt][ldsOffIt[it]]);
                async_cp16(G + (size_t)gSrcRow(nu, rIt[it]) * D_SZ
                             + sccIt[it] + (size_t)nd * 64,
                           &Gsl[nxt][ldsOffIt[it]]);
            }
        }
        intx8 af[2], gf[2];
        #pragma unroll
        for (int t = 0; t < 2; ++t) {
            int4 lo = *(const int4*)&Asl[cur][aAddr[t][0]];
            int4 hi = *(const int4*)&Asl[cur][aAddr[t][1]];
            af[t][0] = lo.x; af[t][1] = lo.y; af[t][2] = lo.z; af[t][3] = lo.w;
            af[t][4] = hi.x; af[t][5] = hi.y; af[t][6] = hi.z; af[t][7] = hi.w;
            int4 glo = *(const int4*)&Gsl[cur][gAddr[t][0]];
            int4 ghi = *(const int4*)&Gsl[cur][gAddr[t][1]];
            gf[t][0] = glo.x; gf[t][1] = glo.y; gf[t][2] = glo.z; gf[t][3] = glo.w;
            gf[t][4] = ghi.x; gf[t][5] = ghi.y; gf[t][6] = ghi.z; gf[t][7] = ghi.w;
        }
        #pragma unroll
        for (int tm = 0; tm < 2; ++tm)
            #pragma unroll
            for (int tn = 0; tn < 2; ++tn)
                acc[tm][tn] = __builtin_amdgcn_mfma_scale_f32_32x32x64_f8f6f4(
                    gf[tm], af[tn], acc[tm][tn],
                    0, 0,                       // cbsz/blgp = fp8 e4m3
                    0, 0x7f7f7f7f,              // scale A: all-ones (2^0)
                    0, 0x7f7f7f7f);             // scale B: all-ones (2^0)

        if (dblk == 7) {
            const int u = iter >> 3;
            if (nPass == 1) {
                // pure tile: no select; rj chosen by hSel (block-uniform)
                #pragma unroll
                for (int tm = 0; tm < 2; ++tm) {
                    #pragma unroll
                    for (int reg = 0; reg < 16; ++reg) {
                        int s = s0 + wm * 64 + tm * 32
                              + (reg & 3) + 8 * (reg >> 2) + 4 * q;
                        float4 md = smeta[s];
                        float rj = hSel ? md.y : md.x;
                        #pragma unroll
                        for (int tn = 0; tn < 2; ++tn) {
                            float logit = acc[tm][tn][reg] * riv[tn] * rj;
                            pe[tn] += __expf(logit);
                            pc[tn] += (logit > pv[tn]) ? 1.f : 0.f;
                        }
                    }
                }
            } else {
                // mixed pass u: pairs [s0+u*64, +64), both candidates staged
                const int sBase = s0 + u * 64;
                #pragma unroll
                for (int tm = 0; tm < 2; ++tm) {
                    #pragma unroll
                    for (int j = 0; j < 4; ++j) {
                        int sp = sBase + wm * 32 + tm * 16 + 4 * j + 2 * q;
                        float4 m0 = smeta[sp];
                        float4 m1 = smeta[sp + 1];
                        #pragma unroll
                        for (int p = 0; p < 2; ++p) {
                            float4 md = p ? m1 : m0;
                            int c0 = __float_as_int(md.z);
                            int re = 4 * j + 2 * p;
                            #pragma unroll
                            for (int tn = 0; tn < 2; ++tn) {
                                bool sel = (c0 >= anc[tn]);   // use c0+1
                                float v = sel ? acc[tm][tn][re + 1]
                                              : acc[tm][tn][re];
                                float rj = sel ? md.y : md.x;
                                float logit = v * riv[tn] * rj;
                                pe[tn] += __expf(logit);
                                pc[tn] += (logit > pv[tn]) ? 1.f : 0.f;
                            }
                        }
                    }
                }
            }
            // reset acc for next pass
            #pragma unroll
            for (int tm = 0; tm < 2; ++tm)
                #pragma unroll
                for (int tn = 0; tn < 2; ++tn)
                    #pragma unroll
                    for (int e = 0; e < 16; ++e)
                        acc[tm][tn][e] = 0.f;
        }
    }

    #pragma unroll
    for (int tn = 0; tn < 2; ++tn) {
        pe[tn] += __shfl_xor(pe[tn], 32);
        pc[tn] += __shfl_xor(pc[tn], 32);
        if (q == 0) {
            atomicAdd(&rowacc[anc[tn]], pe[tn]);
            atomicAdd(&rowacc[B_SZ + anc[tn]], pc[tn]);
        }
    }
}

// ---------------------------------------------------------------------------
// Kernel 3: tiny finalize — one thread per row, then block+global reduce.
// ---------------------------------------------------------------------------
__global__ __launch_bounds__(256) void k_final(
    const float* __restrict__ rowacc, const float* __restrict__ pos_arr,
    float* __restrict__ out)
{
    int row = blockIdx.x * 256 + threadIdx.x;
    float pe = rowacc[row];
    float pc = rowacc[B_SZ + row];
    float pos = pos_arr[row];
    float loss = logf(__expf(pos) + pe) - pos;   // logsumexp - pos (logits bounded)
    float a1 = (pc < 0.5f) ? 1.f : 0.f;          // no neg strictly > pos
    float a5 = (pc < 4.5f) ? 1.f : 0.f;          // at most 4 negs strictly > pos
    for (int m = 1; m < 64; m <<= 1) {
        loss += __shfl_xor(loss, m);
        a1 += __shfl_xor(a1, m);
        a5 += __shfl_xor(a5, m);
    }
    __shared__ float red[3][4];
    int w = threadIdx.x >> 6, l = threadIdx.x & 63;
    if (l == 0) { red[0][w] = loss; red[1][w] = a1; red[2][w] = a5; }
    __syncthreads();
    if (threadIdx.x == 0) {
        float L = red[0][0] + red[0][1] + red[0][2] + red[0][3];
        float A1 = red[1][0] + red[1][1] + red[1][2] + red[1][3];
        float A5 = red[2][0] + red[2][1] + red[2][2] + red[2][3];
        atomicAdd(&out[0], L / (float)B_SZ);
        atomicAdd(&out[1], A1 * (100.f / (float)B_SZ));
        atomicAdd(&out[2], A5 * (100.f / (float)B_SZ));
    }
}

// ---------------------------------------------------------------------------
extern "C" void kernel_launch(void* const* d_in, const int* in_sizes, int n_in,
                              void* d_out, int out_size, void* d_ws, size_t ws_size,
                              hipStream_t stream)
{
    const float* zi = (const float*)d_in[0];
    const float* zj = (const float*)d_in[1];
    const int* perm = (const int*)d_in[2];
    float* out = (float*)d_out;

    // workspace layout (all 16B aligned)
    char* p = (char*)d_ws;
    unsigned char* A = (unsigned char*)p;    p += (size_t)B_SZ * D_SZ;          // 4 MB
    unsigned char* G = (unsigned char*)p;    p += (size_t)2 * K_SZ * D_SZ;      // 2 MB
    float* ri_arr = (float*)p;               p += (size_t)B_SZ * 4;
    float* pos_arr = (float*)p;              p += (size_t)B_SZ * 4;
    float4* smeta = (float4*)p;              p += (size_t)K_SZ * 16;            // 32 KB
    float* rowacc = (float*)p;               p += (size_t)2 * B_SZ * 4;         // 64 KB
    int* pbound = (int*)p;                   p += 128 * 4;

    k_prep<<<3073, 256, 0, stream>>>(zi, zj, perm, ri_arr, pos_arr, A,
                                     smeta, G, pbound, rowacc, out);
    k_gemm<<<1024, 256, 0, stream>>>(A, G, smeta, pbound, ri_arr, pos_arr, rowacc);
    k_final<<<32, 256, 0, stream>>>(rowacc, pos_arr, out);
}

// Round 16
// 112.474 us; speedup vs baseline: 1.0994x; 1.0994x over previous
//
#include <hip/hip_runtime.h>
#include <cstdint>

#define B_SZ 8192
#define D_SZ 512
#define K_SZ 2048
#define EPSV 1e-8f
// 1/TEMP
#define INV_T 2.0f

typedef float floatx16 __attribute__((ext_vector_type(16)));
typedef int intx8 __attribute__((ext_vector_type(8)));

// async global->LDS, 16B per lane. LDS dest must be wave-uniform base + lane*16.
__device__ __forceinline__ void async_cp16(const void* g, void* l) {
    typedef __attribute__((address_space(1))) unsigned int gds_t;
    typedef __attribute__((address_space(3))) unsigned int lds_t;
    __builtin_amdgcn_global_load_lds((gds_t*)(unsigned long long)g, (lds_t*)l, 16, 0, 0);
}

// pack 8 fp32 -> 8 fp8 e4m3 (OCP, RNE, saturating) as int2
__device__ __forceinline__ int2 pack_fp8x8(float4 a0, float4 a1) {
    int w0 = __builtin_amdgcn_cvt_pk_fp8_f32(a0.x, a0.y, 0, false);
    w0 = __builtin_amdgcn_cvt_pk_fp8_f32(a0.z, a0.w, w0, true);
    int w1 = __builtin_amdgcn_cvt_pk_fp8_f32(a1.x, a1.y, 0, false);
    w1 = __builtin_amdgcn_cvt_pk_fp8_f32(a1.z, a1.w, w1, true);
    return make_int2(w0, w1);
}

// ---------------------------------------------------------------------------
// Kernel 1 (merged prep+gather):
//  blocks [0,2048):  per-row norms of z_i/z_j, positive logit, z_i -> fp8 A.
//    Blocks [0,64) also zero the per-row atomic accumulators rowacc[16384]
//    (harness poisons ws with 0xAA); block 0 zeroes d_out.
//  blocks [2048,3072): gather 2K=4096 rows (c_k, c_k+1) of z_j -> fp8 G +
//    per-column-pair metadata kmeta[k] = {1/nj(c), 1/nj(c+1), c0}.
// ---------------------------------------------------------------------------
__global__ __launch_bounds__(256) void k_prep(
    const float* __restrict__ zi, const float* __restrict__ zj,
    const int* __restrict__ perm,
    float* __restrict__ ri_arr, float* __restrict__ pos_arr,
    unsigned char* __restrict__ A,
    float4* __restrict__ kmeta, unsigned char* __restrict__ G,
    float* __restrict__ rowacc, float* __restrict__ out)
{
    int w = threadIdx.x >> 6, l = threadIdx.x & 63;
    if (blockIdx.x < 2048) {
        if (blockIdx.x < 64)
            rowacc[blockIdx.x * 256 + threadIdx.x] = 0.f;   // pe[8192] ++ pc[8192]
        if (blockIdx.x == 0 && threadIdx.x < 3) out[threadIdx.x] = 0.f;
        int row = blockIdx.x * 4 + w;
        const float4* zi4 = (const float4*)(zi + (size_t)row * D_SZ);
        const float4* zj4 = (const float4*)(zj + (size_t)row * D_SZ);
        float4 a0 = zi4[2 * l], a1 = zi4[2 * l + 1];
        float4 b0 = zj4[2 * l], b1 = zj4[2 * l + 1];
        float si = a0.x * a0.x + a0.y * a0.y + a0.z * a0.z + a0.w * a0.w
                 + a1.x * a1.x + a1.y * a1.y + a1.z * a1.z + a1.w * a1.w;
        float sj = b0.x * b0.x + b0.y * b0.y + b0.z * b0.z + b0.w * b0.w
                 + b1.x * b1.x + b1.y * b1.y + b1.z * b1.z + b1.w * b1.w;
        float dd = a0.x * b0.x + a0.y * b0.y + a0.z * b0.z + a0.w * b0.w
                 + a1.x * b1.x + a1.y * b1.y + a1.z * b1.z + a1.w * b1.w;
        for (int m = 1; m < 64; m <<= 1) {
            si += __shfl_xor(si, m);
            sj += __shfl_xor(sj, m);
            dd += __shfl_xor(dd, m);
        }
        if (l == 0) {
            float ni = sqrtf(si), nj = sqrtf(sj);
            ri_arr[row] = INV_T / fmaxf(ni, 1e-6f);   // norms ~22; eps never binds
            pos_arr[row] = dd / fmaxf(ni * nj, EPSV) * INV_T;
        }
        *(int2*)(A + (size_t)row * D_SZ + l * 8) = pack_fp8x8(a0, a1);
    } else {
        __shared__ float srj[4];
        int g = (blockIdx.x - 2048) * 4 + w;        // 0..4095
        int c0 = perm[g >> 1];
        int c = c0 + (g & 1);                       // actual z_j row
        const float4* src = (const float4*)(zj + (size_t)c * D_SZ);
        float4 a0 = src[2 * l], a1 = src[2 * l + 1];
        float s = a0.x * a0.x + a0.y * a0.y + a0.z * a0.z + a0.w * a0.w
                + a1.x * a1.x + a1.y * a1.y + a1.z * a1.z + a1.w * a1.w;
        for (int m = 1; m < 64; m <<= 1) s += __shfl_xor(s, m);
        if (l == 0) srj[w] = 1.0f / fmaxf(sqrtf(s), 1e-6f);
        __syncthreads();
        if ((w & 1) == 0 && l == 0)
            kmeta[g >> 1] = make_float4(srj[w], srj[w + 1],
                                        __int_as_float(c0), 0.f);
        *(int2*)(G + (size_t)g * D_SZ + l * 8) = pack_fp8x8(a0, a1);
    }
}

// ---------------------------------------------------------------------------
// Kernel 2: MX-fp8 MFMA GEMM, TRANSPOSED OUTPUT: S^T = G . A^T (R13 config —
// measured best: 111.0 us total, 0 bank conflicts, FETCH 17.8 MB).
// v_mfma_scale_f32_32x32x64_f8f6f4, unit scales (= plain e4m3 numerics).
// anchor = col = lane, g = row = reg -> in-register reduction; pair-select
// epilogue (one exp per used logit). 128x128 tile, BK=64, 2x2 waves, dbuf
// LDS 2x(8+8) KB, 16B-chunk swizzle slot = c ^ ((r^(r>>2))&3).
// Epilogue atomicAdds per-anchor pe/pc into rowacc[2][8192] (64 adds/address).
// XCD-aware mapping: xcd = bid&7 owns a 512-row G slab (L2-resident).
// ---------------------------------------------------------------------------
__global__ __launch_bounds__(256, 4) void k_gemm(
    const unsigned char* __restrict__ A,    // [8192][512] fp8  (anchors)
    const unsigned char* __restrict__ G,    // [4096][512] fp8  (gathered)
    const float4* __restrict__ kmeta,       // [2048]  {rj0, rj1, c0f, -}
    const float* __restrict__ ri_arr,       // [8192]  INV_T/ni
    const float* __restrict__ pos_arr,      // [8192]
    float* __restrict__ rowacc)             // [2][8192] atomic accumulators
{
    __shared__ unsigned char Asl[2][128 * 64];   // anchor tile, 8 KB per buffer
    __shared__ unsigned char Gsl[2][128 * 64];   // g tile
    const int tid = threadIdx.x;
    const int l = tid & 63, w = tid >> 6;
    const int wm = w >> 1, wn = w & 1;      // wm: g-half, wn: anchor-half
    const int ln = l & 31, q = l >> 5;      // 32x32 MFMA lane decomposition

    // XCD-aware tile mapping: 2048 blocks; xcd = bid&7 owns g-slab xcd*4..+4
    const int bid = blockIdx.x;
    const int xcd = bid & 7;
    const int slot = bid >> 3;              // 0..255
    const int gTile = xcd * 4 + (slot & 3); // 0..31 (G row panel)
    const int aTile = slot >> 2;            // 0..63 (anchor panel)
    const int gBase = gTile * 128;
    const int aBase = aTile * 128;

    // staging offsets (bytes); 512 16B-chunks per array per dblk (2 iters x 256)
    size_t aOff[2], gOff[2];
    int ldsOff[2];
    #pragma unroll
    for (int it = 0; it < 2; ++it) {
        int fc = it * 256 + tid;            // 16B chunk 0..511
        int r = fc >> 2, s = fc & 3;
        int scc = s ^ ((r ^ (r >> 2)) & 3); // XOR swizzle source 16B chunk
        aOff[it] = (size_t)(aBase + r) * D_SZ + scc * 16;
        gOff[it] = (size_t)(gBase + r) * D_SZ + scc * 16;
        ldsOff[it] = fc * 16;
    }

    floatx16 acc[2][2] = {};                // [tm: g-subtile][tn: anchor-subtile]

    // frag read addresses (bytes in an 8 KB buffer): lane needs k-bytes
    // [q*32, q*32+32) of its row = pre-swizzle chunks {2q, 2q+1}
    int aAddr[2][2], gAddr[2][2];           // [t][chunk half]
    #pragma unroll
    for (int t = 0; t < 2; ++t) {
        int ar = wn * 64 + t * 32 + ln;     // anchor row (N-operand)
        int xa = (ar ^ (ar >> 2)) & 3;
        aAddr[t][0] = ar * 64 + ((2 * q) ^ xa) * 16;
        aAddr[t][1] = ar * 64 + ((2 * q + 1) ^ xa) * 16;
        int gr = wm * 64 + t * 32 + ln;     // g row (M-operand)
        int xg = (gr ^ (gr >> 2)) & 3;
        gAddr[t][0] = gr * 64 + ((2 * q) ^ xg) * 16;
        gAddr[t][1] = gr * 64 + ((2 * q + 1) ^ xg) * 16;
    }

    // prologue: stage k-block 0 into buffer 0
    #pragma unroll
    for (int it = 0; it < 2; ++it) {
        async_cp16(A + aOff[it], &Asl[0][ldsOff[it]]);
        async_cp16(G + gOff[it], &Gsl[0][ldsOff[it]]);
    }

    #pragma unroll 1
    for (int dblk = 0; dblk < 8; ++dblk) {
        const int cur = dblk & 1, nxt = cur ^ 1;
        __syncthreads();                    // staged data for `cur` is ready
        if (dblk < 7) {
            #pragma unroll
            for (int it = 0; it < 2; ++it) {
                async_cp16(A + aOff[it] + (size_t)(dblk + 1) * 64, &Asl[nxt][ldsOff[it]]);
                async_cp16(G + gOff[it] + (size_t)(dblk + 1) * 64, &Gsl[nxt][ldsOff[it]]);
            }
        }
        intx8 af[2], gf[2];
        #pragma unroll
        for (int t = 0; t < 2; ++t) {
            int4 lo = *(const int4*)&Asl[cur][aAddr[t][0]];
            int4 hi = *(const int4*)&Asl[cur][aAddr[t][1]];
            af[t][0] = lo.x; af[t][1] = lo.y; af[t][2] = lo.z; af[t][3] = lo.w;
            af[t][4] = hi.x; af[t][5] = hi.y; af[t][6] = hi.z; af[t][7] = hi.w;
            int4 glo = *(const int4*)&Gsl[cur][gAddr[t][0]];
            int4 ghi = *(const int4*)&Gsl[cur][gAddr[t][1]];
            gf[t][0] = glo.x; gf[t][1] = glo.y; gf[t][2] = glo.z; gf[t][3] = glo.w;
            gf[t][4] = ghi.x; gf[t][5] = ghi.y; gf[t][6] = ghi.z; gf[t][7] = ghi.w;
        }
        #pragma unroll
        for (int tm = 0; tm < 2; ++tm)
            #pragma unroll
            for (int tn = 0; tn < 2; ++tn)
                acc[tm][tn] = __builtin_amdgcn_mfma_scale_f32_32x32x64_f8f6f4(
                    gf[tm], af[tn], acc[tm][tn],
                    0, 0,                       // cbsz/blgp = fp8 e4m3
                    0, 0x7f7f7f7f,              // scale A: all-ones (2^0)
                    0, 0x7f7f7f7f);             // scale B: all-ones (2^0)
    }

    // ---- fused epilogue: pair-select then exp, in-register reduction ----
    // C/D layout (32x32): col = anchor = ln (+tn*32), row = g = (reg&3) +
    // 8*(reg>>2) + 4*q (+tm*32). Regs 4j..4j+3 hold 4 consecutive g, i.e.
    // column pairs k0 = gTile*64 + wm*32 + tm*16 + 4j + 2q and k0+1.
    int anc[2]; float riv[2], pv[2], pe[2] = {0.f, 0.f}, pc[2] = {0.f, 0.f};
    #pragma unroll
    for (int tn = 0; tn < 2; ++tn) {
        anc[tn] = aBase + wn * 64 + tn * 32 + ln;
        riv[tn] = ri_arr[anc[tn]];          // INV_T / ni
        pv[tn] = pos_arr[anc[tn]];
    }
    #pragma unroll
    for (int tm = 0; tm < 2; ++tm) {
        #pragma unroll
        for (int j = 0; j < 4; ++j) {
            int k0 = gTile * 64 + wm * 32 + tm * 16 + 4 * j + 2 * q;
            float4 m0 = kmeta[k0];
            float4 m1 = kmeta[k0 + 1];
            #pragma unroll
            for (int p = 0; p < 2; ++p) {
                float4 md = p ? m1 : m0;
                int c0 = __float_as_int(md.z);
                int re = 4 * j + 2 * p;     // even-g reg; odd is re+1
                #pragma unroll
                for (int tn = 0; tn < 2; ++tn) {
                    bool sel = (c0 >= anc[tn]);             // use column c0+1
                    float v = sel ? acc[tm][tn][re + 1] : acc[tm][tn][re];
                    float rj = sel ? md.y : md.x;
                    float logit = v * riv[tn] * rj;
                    pe[tn] += __expf(logit);
                    pc[tn] += (logit > pv[tn]) ? 1.f : 0.f;
                }
            }
        }
    }
    #pragma unroll
    for (int tn = 0; tn < 2; ++tn) {
        pe[tn] += __shfl_xor(pe[tn], 32);
        pc[tn] += __shfl_xor(pc[tn], 32);
        if (q == 0) {
            atomicAdd(&rowacc[anc[tn]], pe[tn]);
            atomicAdd(&rowacc[B_SZ + anc[tn]], pc[tn]);
        }
    }
}

// ---------------------------------------------------------------------------
// Kernel 3: tiny finalize — one thread per row, then block+global reduce.
// 32 blocks x 256 threads; reads only rowacc[2][8192] + pos_arr.
// ---------------------------------------------------------------------------
__global__ __launch_bounds__(256) void k_final(
    const float* __restrict__ rowacc, const float* __restrict__ pos_arr,
    float* __restrict__ out)
{
    int row = blockIdx.x * 256 + threadIdx.x;
    float pe = rowacc[row];
    float pc = rowacc[B_SZ + row];
    float pos = pos_arr[row];
    float loss = logf(__expf(pos) + pe) - pos;   // logsumexp - pos (logits bounded)
    float a1 = (pc < 0.5f) ? 1.f : 0.f;          // no neg strictly > pos
    float a5 = (pc < 4.5f) ? 1.f : 0.f;          // at most 4 negs strictly > pos
    for (int m = 1; m < 64; m <<= 1) {
        loss += __shfl_xor(loss, m);
        a1 += __shfl_xor(a1, m);
        a5 += __shfl_xor(a5, m);
    }
    __shared__ float red[3][4];
    int w = threadIdx.x >> 6, l = threadIdx.x & 63;
    if (l == 0) { red[0][w] = loss; red[1][w] = a1; red[2][w] = a5; }
    __syncthreads();
    if (threadIdx.x == 0) {
        float L = red[0][0] + red[0][1] + red[0][2] + red[0][3];
        float A1 = red[1][0] + red[1][1] + red[1][2] + red[1][3];
        float A5 = red[2][0] + red[2][1] + red[2][2] + red[2][3];
        atomicAdd(&out[0], L / (float)B_SZ);
        atomicAdd(&out[1], A1 * (100.f / (float)B_SZ));
        atomicAdd(&out[2], A5 * (100.f / (float)B_SZ));
    }
}

// ---------------------------------------------------------------------------
extern "C" void kernel_launch(void* const* d_in, const int* in_sizes, int n_in,
                              void* d_out, int out_size, void* d_ws, size_t ws_size,
                              hipStream_t stream)
{
    const float* zi = (const float*)d_in[0];
    const float* zj = (const float*)d_in[1];
    const int* perm = (const int*)d_in[2];
    float* out = (float*)d_out;

    // workspace layout (all 16B aligned)
    char* p = (char*)d_ws;
    unsigned char* A = (unsigned char*)p;    p += (size_t)B_SZ * D_SZ;          // 4 MB
    unsigned char* G = (unsigned char*)p;    p += (size_t)2 * K_SZ * D_SZ;      // 2 MB
    float* ri_arr = (float*)p;               p += (size_t)B_SZ * 4;
    float* pos_arr = (float*)p;              p += (size_t)B_SZ * 4;
    float4* kmeta = (float4*)p;              p += (size_t)K_SZ * 16;            // 32 KB
    float* rowacc = (float*)p;               p += (size_t)2 * B_SZ * 4;         // 64 KB

    k_prep<<<2048 + 1024, 256, 0, stream>>>(zi, zj, perm, ri_arr, pos_arr, A,
                                            kmeta, G, rowacc, out);
    k_gemm<<<2048, 256, 0, stream>>>(A, G, kmeta, ri_arr, pos_arr, rowacc);
    k_final<<<32, 256, 0, stream>>>(rowacc, pos_arr, out);
}